// Round 12
// baseline (9656.059 us; speedup 1.0000x reference)
//
#include <hip/hip_runtime.h>

// BiLSTM(128->2x256) -> LayerNorm(512) -> BiLSTM(512->2x256), B=64 T=1024.
// f16 MFMA inputs, f32 accum/cell. Recurrence: 16 persistent WGs x 576 thr
// = (2 u-half x 2 dir x 4 batch-group), 8 compute waves + 1 COMM WAVE each.
// Each WG holds HALF of U(dir) in registers (128 B-regs/wave, spill-free).
// The comm wave alone polls the partner WG's published h block (sentinel
// protocol, device-coherent sc0|sc1 loads -> L3) and deposits it in LDS;
// compute waves read BOTH halves of h(t-1) from LDS. The poll round trip
// overlaps compute waves' gates/publish; poll traffic deduplicated 8x; the
// comm wave's vmcnt is clean (no publish acks). Sync = per-step s_barrier.

typedef __attribute__((ext_vector_type(8))) _Float16 half8;    // f16x8 MFMA frag
typedef __attribute__((ext_vector_type(4))) float f32x4;       // MFMA acc
typedef __attribute__((ext_vector_type(4))) unsigned short ushort4v;
typedef __attribute__((ext_vector_type(4))) unsigned int uint4v;

#define LOG2E 1.4426950408889634f
#define SENTW 0xFFFFFFFFu

static __device__ __forceinline__ unsigned short f2h(float f) {
  _Float16 h = (_Float16)f;
  return __builtin_bit_cast(unsigned short, h);
}
static __device__ __forceinline__ float h2f(unsigned short u) {
  _Float16 h = __builtin_bit_cast(_Float16, u);
  return (float)h;
}
static __device__ __forceinline__ float sigf(float x) {
  return __builtin_amdgcn_rcpf(1.f + __builtin_amdgcn_exp2f(-LOG2E * x));
}
static __device__ __forceinline__ float tanhf_(float x) {
  return 1.f - 2.f * __builtin_amdgcn_rcpf(__builtin_amdgcn_exp2f((2.f * LOG2E) * x) + 1.f);
}

// Device-coherent (L3 coherence point) access helpers: sc0|sc1 bypass L1/L2.
static __device__ __forceinline__ uint4v ld_b128_dev(const uint4v* p) {
  uint4v v; asm volatile("global_load_dwordx4 %0, %1, off sc0 sc1" : "=v"(v) : "v"(p)); return v;
}
static __device__ __forceinline__ void st_b32_dev(unsigned* p, unsigned v) {
  asm volatile("global_store_dword %0, %1, off sc0 sc1" :: "v"(p), "v"(v) : "memory");
}
static __device__ __forceinline__ bool nosent(const uint4v& v) {
  return v.x != SENTW && v.y != SENTW && v.z != SENTW && v.w != SENTW;
}

// fill n16 16-byte chunks with the sentinel pattern
__global__ void k_fill(uint4v* p, unsigned n16) {
  const uint4v v = (uint4v){SENTW, SENTW, SENTW, SENTW};
  for (unsigned i = blockIdx.x * 256 + threadIdx.x; i < n16; i += gridDim.x * 256)
    p[i] = v;
}

// out[c][k] = f16(in[k][c]); in is [K][1024] f32, out is [1024][K] f16.
__global__ void k_transpose(const float* __restrict__ in, unsigned short* __restrict__ out, int K) {
  int idx = blockIdx.x * 256 + threadIdx.x;
  int c = idx / K, k = idx - c * K;
  out[idx] = f2h(in[k * 1024 + c]);
}

// x [b][t][128] f32 -> xb [(t*64+b)][128] f16
__global__ void k_cvtx(const float* __restrict__ x, unsigned short* __restrict__ xb) {
  int i = blockIdx.x * 256 + threadIdx.x;
  int o = i * 4;
  int k = o & 127, row = o >> 7;
  int b = row & 63, t = row >> 6;
  const f32x4 v = *(const f32x4*)(x + (size_t)((b << 10) + t) * 128 + k);
  ushort4v r;
  r.x = f2h(v.x); r.y = f2h(v.y); r.z = f2h(v.z); r.w = f2h(v.w);
  *(ushort4v*)(xb + o) = r;
}

// zx GEMM: A [65536 rows=(t*64+b)][K] f16 times Wt [1024][K] f16 (+bias)
// -> out [1024 t][1024 col][64 b] f16.  128x128 tiles, direct-global frags.
template<int K>
__global__ __launch_bounds__(256, 2) void k_zx(
    const unsigned short* __restrict__ A,
    const unsigned short* __restrict__ Wt_f, const unsigned short* __restrict__ Wt_b,
    const float* __restrict__ bias_f, const float* __restrict__ bias_b,
    unsigned short* __restrict__ out_f, unsigned short* __restrict__ out_b) {
  const int tid = threadIdx.x, w = tid >> 6, l = tid & 63;
  const int l16 = l & 15, lg = l >> 4;
  const int wm = w & 1, wn = w >> 1;
  const int rowbase = blockIdx.x * 128 + wm * 64;
  const int colbase = blockIdx.y * 128 + wn * 64;
  const unsigned short* Wt = blockIdx.z ? Wt_b : Wt_f;
  const float* bias = blockIdx.z ? bias_b : bias_f;
  unsigned short* out = blockIdx.z ? out_b : out_f;

  f32x4 acc[4][4];
#pragma unroll
  for (int nt = 0; nt < 4; nt++) {
    float bv = bias[colbase + nt * 16 + l16];
#pragma unroll
    for (int mt = 0; mt < 4; mt++) acc[mt][nt] = (f32x4){bv, bv, bv, bv};
  }

  for (int kf = 0; kf < K / 32; kf++) {
    const int ko = kf * 32 + lg * 8;
    half8 a[4], b[4];
#pragma unroll
    for (int mt = 0; mt < 4; mt++)
      a[mt] = *(const half8*)(A + (size_t)(rowbase + mt * 16 + l16) * K + ko);
#pragma unroll
    for (int nt = 0; nt < 4; nt++)
      b[nt] = *(const half8*)(Wt + (size_t)(colbase + nt * 16 + l16) * K + ko);
#pragma unroll
    for (int mt = 0; mt < 4; mt++)
#pragma unroll
      for (int nt = 0; nt < 4; nt++)
        acc[mt][nt] = __builtin_amdgcn_mfma_f32_16x16x32_f16(a[mt], b[nt], acc[mt][nt], 0, 0, 0);
  }

#pragma unroll
  for (int mt = 0; mt < 4; mt++) {
    const int rowchunk = rowbase + mt * 16;
    const int t = rowchunk >> 6;
    const int b0 = (rowchunk & 63) + lg * 4;
#pragma unroll
    for (int nt = 0; nt < 4; nt++) {
      const int c = colbase + nt * 16 + l16;
      ushort4v r;
      r.x = f2h(acc[mt][nt].x); r.y = f2h(acc[mt][nt].y);
      r.z = f2h(acc[mt][nt].z); r.w = f2h(acc[mt][nt].w);
      *(ushort4v*)(out + (((size_t)t << 10 | c) << 6) + b0) = r;
    }
  }
}

// Persistent recurrence. 16 WGs x 576 thr: bid = half*8 + d*4 + g.
// Waves 0..7 compute (u-tile of 16 each, half-U resident); wave 8 = comm.
// Exchange: L1 exch = h1 [(tt*64+b)][512] (doubles as LN input);
//           L2 exch = hist [t][d][g][half][16 b][128 u].
template<int LAYER>
__global__ __launch_bounds__(576, 1) void k_rec8(
    const unsigned short* __restrict__ zx_f, const unsigned short* __restrict__ zx_b,
    const unsigned short* __restrict__ Ut_f, const unsigned short* __restrict__ Ut_b,
    unsigned short* __restrict__ exch,
    float* __restrict__ out) {           // LAYER==2: [b][t][512] f32
  const int tid = threadIdx.x, wv = tid >> 6, l = tid & 63;
  const int l16 = l & 15, lg = l >> 4;
  const int bid = blockIdx.x;
  const int half = bid >> 3, d = (bid >> 2) & 1, g = bid & 3;
  const int b0 = g * 16;
  const int swz = (l16 & 7) << 3;

  const unsigned short* zx = d ? zx_b : zx_f;
  const unsigned short* Ut = d ? Ut_b : Ut_f;

  // [slot][16 b][128 u], XOR-swizzled rows; own half + partner half
  __shared__ unsigned short hlds[2 * 2048];
  __shared__ unsigned short plds[2 * 2048];

  if (wv == 8) {
    // ------------------- comm wave -------------------
    for (int t = 0; t < 1024; t++) {
      if (t < 1023) {
        // partner block published at step t (consumed by compute at t+1)
        const uint4v* rowp;
        if constexpr (LAYER == 1) {
          const int trow = d ? 1023 - t : t;
          rowp = (const uint4v*)(exch + ((size_t)trow * 64 + b0 + l16) * 512 + d * 256 + (half ^ 1) * 128);
        } else {
          rowp = (const uint4v*)(exch + (((((size_t)t * 2 + d) * 4 + g) * 2 + (half ^ 1)) * 2048)
                                 + (size_t)l16 * 128);
        }
        uint4v v0 = ld_b128_dev(rowp + 0 + lg);
        uint4v v1 = ld_b128_dev(rowp + 4 + lg);
        uint4v v2 = ld_b128_dev(rowp + 8 + lg);
        uint4v v3 = ld_b128_dev(rowp + 12 + lg);
        int tries = 0;
        while (true) {
          asm volatile("s_waitcnt vmcnt(0)" ::: "memory");
          __builtin_amdgcn_sched_barrier(0);
          if (__all(nosent(v0) && nosent(v1) && nosent(v2) && nosent(v3))) break;
          if (++tries > (1 << 16)) break;   // anti-hang bail
          v0 = ld_b128_dev(rowp + 0 + lg);
          v1 = ld_b128_dev(rowp + 4 + lg);
          v2 = ld_b128_dev(rowp + 8 + lg);
          v3 = ld_b128_dev(rowp + 12 + lg);
        }
        __builtin_amdgcn_sched_barrier(0);
        unsigned short* pb = plds + (t & 1) * 2048;
        *(uint4v*)&pb[(l16 * 128 + 0 * 32 + lg * 8) ^ swz] = v0;
        *(uint4v*)&pb[(l16 * 128 + 1 * 32 + lg * 8) ^ swz] = v1;
        *(uint4v*)&pb[(l16 * 128 + 2 * 32 + lg * 8) ^ swz] = v2;
        *(uint4v*)&pb[(l16 * 128 + 3 * 32 + lg * 8) ^ swz] = v3;
      }
      asm volatile("s_waitcnt lgkmcnt(0)" ::: "memory");
      __builtin_amdgcn_s_barrier();
    }
    return;
  }

  // ------------------- compute waves (wv 0..7) -------------------
  const int ug = half * 128 + wv * 16 + l16;   // this lane's u in [0,256)

  // B[q][j]: j 0..3 = OWN kf (half*4+j), j 4..7 = REMOTE kf ((half^1)*4+j-4)
  half8 B[4][8];
#pragma unroll
  for (int j = 0; j < 8; j++) {
    const int kf = (j < 4) ? (half * 4 + j) : ((half ^ 1) * 4 + (j - 4));
#pragma unroll
    for (int q = 0; q < 4; q++)
      B[q][j] = *(const half8*)(Ut + (size_t)(q * 256 + ug) * 256 + kf * 32 + lg * 8);
  }

  f32x4 c = (f32x4){0, 0, 0, 0};

  ushort4v zq[4];
  {
    const int t0 = d ? 1023 : 0;
#pragma unroll
    for (int q = 0; q < 4; q++)
      zq[q] = *(const ushort4v*)(zx + (((size_t)t0 << 10 | (q * 256 + ug)) << 6) + b0 + lg * 4);
  }

  for (int t = 0; t < 1024; t++) {
    const int tt = d ? 1023 - t : t;
    f32x4 acc[4];
#pragma unroll
    for (int q = 0; q < 4; q++)
      acc[q] = (f32x4){h2f(zq[q].x), h2f(zq[q].y), h2f(zq[q].z), h2f(zq[q].w)};

    if (t > 0) {
      const int slot = ((t - 1) & 1) * 2048;
      half8 ha[4], pa[4];
#pragma unroll
      for (int kfo = 0; kfo < 4; kfo++) {
        const int idx = (l16 * 128 + kfo * 32 + lg * 8) ^ swz;   // row b = l16
        ha[kfo] = *(const half8*)&hlds[slot + idx];
        pa[kfo] = *(const half8*)&plds[slot + idx];
      }
#pragma unroll
      for (int kfo = 0; kfo < 4; kfo++)
#pragma unroll
        for (int q = 0; q < 4; q++)
          acc[q] = __builtin_amdgcn_mfma_f32_16x16x32_f16(ha[kfo], B[q][kfo], acc[q], 0, 0, 0);
#pragma unroll
      for (int kfo = 0; kfo < 4; kfo++)
#pragma unroll
        for (int q = 0; q < 4; q++)
          acc[q] = __builtin_amdgcn_mfma_f32_16x16x32_f16(pa[kfo], B[q][4 + kfo], acc[q], 0, 0, 0);
    }

    if (t + 1 < 1024) {   // zx prefetch (plain loads; compiler manages waits)
      const int tn = d ? tt - 1 : tt + 1;
#pragma unroll
      for (int q = 0; q < 4; q++)
        zq[q] = *(const ushort4v*)(zx + (((size_t)tn << 10 | (q * 256 + ug)) << 6) + b0 + lg * 4);
    }

    // gates + state update; D-frag: row(b_local) = lg*4+rr, col(u) = l16
    unsigned short hb16[4];
    float hf[4];
#pragma unroll
    for (int rr = 0; rr < 4; rr++) {
      const float zi = acc[0][rr], zf = acc[1][rr], zg = acc[2][rr], zo = acc[3][rr];
      const float cc = sigf(zf) * c[rr] + sigf(zi) * tanhf_(zg);
      c[rr] = cc;
      hf[rr] = sigf(zo) * tanhf_(cc);
      hb16[rr] = f2h(hf[rr]);
    }

    // publish partner-visible h (pack lane-pairs into 4B device stores)
    {
      unsigned prt[4];
#pragma unroll
      for (int rr = 0; rr < 4; rr++)
        prt[rr] = (unsigned)__shfl_xor((int)(unsigned)hb16[rr], 1);
      const int odd = l16 & 1;
      const int rb = odd ? 2 : 0;
#pragma unroll
      for (int k = 0; k < 2; k++) {
        const int rr = rb + k;
        const int bl = lg * 4 + rr;
        const unsigned lo = odd ? prt[rr] : (unsigned)hb16[rr];
        const unsigned hi = odd ? (unsigned)hb16[rr] : prt[rr];
        const unsigned pk = (lo & 0xffffu) | (hi << 16);
        if constexpr (LAYER == 1) {
          const size_t widx = (((size_t)tt * 64 + b0 + bl) * 512 + d * 256 + (ug & ~1)) >> 1;
          st_b32_dev((unsigned*)exch + widx, pk);
        } else {
          const size_t base = ((((size_t)t * 2 + d) * 4 + g) * 2 + half) * 2048;
          const size_t widx = (base + (size_t)bl * 128 + ((ug & ~1) - half * 128)) >> 1;
          st_b32_dev((unsigned*)exch + widx, pk);
        }
      }
    }

    if constexpr (LAYER == 2) {
#pragma unroll
      for (int rr = 0; rr < 4; rr++) {
        const int b = b0 + lg * 4 + rr;
        out[((size_t)b << 10 | tt) * 512 + d * 256 + ug] = hf[rr];
      }
    }

    // own-half h(t) -> LDS (slot t&1; read next step from this slot)
#pragma unroll
    for (int rr = 0; rr < 4; rr++) {
      const int bl = lg * 4 + rr;
      const int ul = wv * 16 + l16;
      const int idx = ((bl * 128 + ul) ^ ((bl & 7) << 3)) + (t & 1) * 2048;
      hlds[idx] = hb16[rr];
    }

    // raw barrier: LDS ordering only (no vmcnt drain -> publishes fly on)
    asm volatile("s_waitcnt lgkmcnt(0)" ::: "memory");
    __builtin_amdgcn_s_barrier();
  }
}

// LayerNorm over 512 features; one wave per row. f16 in/out, f32 math.
__global__ __launch_bounds__(256) void k_ln(
    const unsigned short* __restrict__ h1, const float* __restrict__ gamma,
    const float* __restrict__ beta, unsigned short* __restrict__ ln1) {
  const int tid = threadIdx.x, w = tid >> 6, l = tid & 63;
  const size_t row = (size_t)blockIdx.x * 4 + w;
  const unsigned short* src = h1 + row * 512 + l * 8;
  const ushort4v v0 = *(const ushort4v*)src;
  const ushort4v v1 = *(const ushort4v*)(src + 4);
  float xv[8] = {h2f(v0.x), h2f(v0.y), h2f(v0.z), h2f(v0.w),
                 h2f(v1.x), h2f(v1.y), h2f(v1.z), h2f(v1.w)};
  float sum = 0.f, ssq = 0.f;
#pragma unroll
  for (int i = 0; i < 8; i++) { sum += xv[i]; ssq += xv[i] * xv[i]; }
#pragma unroll
  for (int off = 32; off; off >>= 1) {
    sum += __shfl_xor(sum, off);
    ssq += __shfl_xor(ssq, off);
  }
  const float mu = sum * (1.f / 512.f);
  const float var = ssq * (1.f / 512.f) - mu * mu;
  const float rs = __builtin_amdgcn_rsqf(var + 1e-3f);
  const f32x4 g0 = *(const f32x4*)(gamma + l * 8);
  const f32x4 g1 = *(const f32x4*)(gamma + l * 8 + 4);
  const f32x4 e0 = *(const f32x4*)(beta + l * 8);
  const f32x4 e1 = *(const f32x4*)(beta + l * 8 + 4);
  float gg[8] = {g0.x, g0.y, g0.z, g0.w, g1.x, g1.y, g1.z, g1.w};
  float ee[8] = {e0.x, e0.y, e0.z, e0.w, e1.x, e1.y, e1.z, e1.w};
  unsigned short hh[8];
#pragma unroll
  for (int i = 0; i < 8; i++)
    hh[i] = f2h((xv[i] - mu) * rs * gg[i] + ee[i]);
  unsigned short* dst = ln1 + row * 512 + l * 8;
  *(ushort4v*)dst = (ushort4v){hh[0], hh[1], hh[2], hh[3]};
  *(ushort4v*)(dst + 4) = (ushort4v){hh[4], hh[5], hh[6], hh[7]};
}

extern "C" void kernel_launch(void* const* d_in, const int* in_sizes, int n_in,
                              void* d_out, int out_size, void* d_ws, size_t ws_size,
                              hipStream_t stream) {
  (void)in_sizes; (void)n_in; (void)out_size; (void)ws_size;
  const float* x     = (const float*)d_in[0];
  const float* W1f   = (const float*)d_in[1];
  const float* U1f   = (const float*)d_in[2];
  const float* b1f   = (const float*)d_in[3];
  const float* W1b   = (const float*)d_in[4];
  const float* U1b   = (const float*)d_in[5];
  const float* b1b   = (const float*)d_in[6];
  const float* gamma = (const float*)d_in[7];
  const float* beta  = (const float*)d_in[8];
  const float* W2f   = (const float*)d_in[9];
  const float* U2f   = (const float*)d_in[10];
  const float* b2f   = (const float*)d_in[11];
  const float* W2b   = (const float*)d_in[12];
  const float* U2b   = (const float*)d_in[13];
  const float* b2b   = (const float*)d_in[14];

  char* ws = (char*)d_ws;
  size_t ofs = 0;
  auto alloc = [&](size_t bytes) -> void* {
    void* p = ws + ofs;
    ofs += (bytes + 255) & ~(size_t)255;
    return p;
  };
  unsigned short* Wt1f  = (unsigned short*)alloc((size_t)1024*128*2);
  unsigned short* Wt1b  = (unsigned short*)alloc((size_t)1024*128*2);
  unsigned short* Ut1f  = (unsigned short*)alloc((size_t)1024*256*2);
  unsigned short* Ut1b  = (unsigned short*)alloc((size_t)1024*256*2);
  unsigned short* Ut2f  = (unsigned short*)alloc((size_t)1024*256*2);
  unsigned short* Ut2b  = (unsigned short*)alloc((size_t)1024*256*2);
  unsigned short* Wt2f  = (unsigned short*)alloc((size_t)1024*512*2);
  unsigned short* Wt2b  = (unsigned short*)alloc((size_t)1024*512*2);
  unsigned short* zxf   = (unsigned short*)alloc((size_t)1024*1024*64*2);  // 128MB
  unsigned short* zxb   = (unsigned short*)alloc((size_t)1024*1024*64*2);  // 128MB
  const size_t HH2_BYTES = (size_t)1024*2*4*2*16*128*2;                    // 64MB
  unsigned short* hist  = (unsigned short*)alloc(HH2_BYTES);               // ws >= 323MB proven

  // d_out (128MB): xb [0,16MB) dead after zx1 -> h1 [0,64MB) sentinel-filled,
  // exchange+output of k_rec8<1>, dead after LN -> ln1 [64,128MB) dead after
  // zx2 -> final f32 out overwrites all 128MB in k_rec8<2>.
  unsigned short* xb  = (unsigned short*)d_out;
  unsigned short* h1  = (unsigned short*)d_out;
  unsigned short* ln1 = (unsigned short*)d_out + (size_t)65536 * 512;

  k_transpose<<<1024 * 128 / 256, 256, 0, stream>>>(W1f, Wt1f, 128);
  k_transpose<<<1024 * 128 / 256, 256, 0, stream>>>(W1b, Wt1b, 128);
  k_transpose<<<1024 * 256 / 256, 256, 0, stream>>>(U1f, Ut1f, 256);
  k_transpose<<<1024 * 256 / 256, 256, 0, stream>>>(U1b, Ut1b, 256);
  k_transpose<<<1024 * 512 / 256, 256, 0, stream>>>(W2f, Wt2f, 512);
  k_transpose<<<1024 * 512 / 256, 256, 0, stream>>>(W2b, Wt2b, 512);
  k_transpose<<<1024 * 256 / 256, 256, 0, stream>>>(U2f, Ut2f, 256);
  k_transpose<<<1024 * 256 / 256, 256, 0, stream>>>(U2b, Ut2b, 256);
  k_cvtx<<<8192, 256, 0, stream>>>(x, xb);

  dim3 zgrid(512, 8, 2);
  k_zx<128><<<zgrid, 256, 0, stream>>>(xb, Wt1f, Wt1b, b1f, b1b, zxf, zxb);
  k_fill<<<2048, 256, 0, stream>>>((uint4v*)h1, 65536u * 512u / 8u);
  k_rec8<1><<<16, 576, 0, stream>>>(zxf, zxb, Ut1f, Ut1b, h1, nullptr);
  k_ln<<<65536 / 4, 256, 0, stream>>>(h1, gamma, beta, ln1);
  k_zx<512><<<zgrid, 256, 0, stream>>>(ln1, Wt2f, Wt2b, b2f, b2b, zxf, zxb);
  k_fill<<<2048, 256, 0, stream>>>((uint4v*)hist, (unsigned)(HH2_BYTES / 16));
  k_rec8<2><<<16, 576, 0, stream>>>(zxf, zxb, Ut2f, Ut2b, hist, (float*)d_out);
}

// Round 13
// 7954.314 us; speedup vs baseline: 1.2139x; 1.2139x over previous
//
#include <hip/hip_runtime.h>

// BiLSTM(128->2x256) -> LayerNorm(512) -> BiLSTM(512->2x256), B=64 T=1024.
// f16 MFMA inputs, f32 accum/cell. Recurrence: 16 persistent WGs x 576 thr
// = (2 u-half x 2 dir x 4 batch-group), 8 compute waves + 1 COMM WAVE each.
// Each WG holds HALF of U(dir) in registers. Per step t the comm wave alone
// fetches the PARTNER block for step t-1 (published one phase ago -> visible
// on first check) and deposits it in LDS; a MID-STEP barrier hands it to the
// compute waves, which did their own-half MFMA during the fetch. The
// publish->visible round trip is absorbed by the next step's comm phase
// instead of serializing. Poll traffic deduplicated 8x; compute waves carry
// no inline vmcnt. Two s_barriers per step (mid + end).

typedef __attribute__((ext_vector_type(8))) _Float16 half8;    // f16x8 MFMA frag
typedef __attribute__((ext_vector_type(4))) float f32x4;       // MFMA acc
typedef __attribute__((ext_vector_type(4))) unsigned short ushort4v;
typedef __attribute__((ext_vector_type(4))) unsigned int uint4v;

#define LOG2E 1.4426950408889634f
#define SENTW 0xFFFFFFFFu

static __device__ __forceinline__ unsigned short f2h(float f) {
  _Float16 h = (_Float16)f;
  return __builtin_bit_cast(unsigned short, h);
}
static __device__ __forceinline__ float h2f(unsigned short u) {
  _Float16 h = __builtin_bit_cast(_Float16, u);
  return (float)h;
}
static __device__ __forceinline__ float sigf(float x) {
  return __builtin_amdgcn_rcpf(1.f + __builtin_amdgcn_exp2f(-LOG2E * x));
}
static __device__ __forceinline__ float tanhf_(float x) {
  return 1.f - 2.f * __builtin_amdgcn_rcpf(__builtin_amdgcn_exp2f((2.f * LOG2E) * x) + 1.f);
}

// Device-coherent (L3 coherence point) access helpers: sc0|sc1 bypass L1/L2.
static __device__ __forceinline__ uint4v ld_b128_dev(const uint4v* p) {
  uint4v v; asm volatile("global_load_dwordx4 %0, %1, off sc0 sc1" : "=v"(v) : "v"(p)); return v;
}
static __device__ __forceinline__ void st_b32_dev(unsigned* p, unsigned v) {
  asm volatile("global_store_dword %0, %1, off sc0 sc1" :: "v"(p), "v"(v) : "memory");
}
static __device__ __forceinline__ bool nosent(const uint4v& v) {
  return v.x != SENTW && v.y != SENTW && v.z != SENTW && v.w != SENTW;
}

// fill n16 16-byte chunks with the sentinel pattern
__global__ void k_fill(uint4v* p, unsigned n16) {
  const uint4v v = (uint4v){SENTW, SENTW, SENTW, SENTW};
  for (unsigned i = blockIdx.x * 256 + threadIdx.x; i < n16; i += gridDim.x * 256)
    p[i] = v;
}

// out[c][k] = f16(in[k][c]); in is [K][1024] f32, out is [1024][K] f16.
__global__ void k_transpose(const float* __restrict__ in, unsigned short* __restrict__ out, int K) {
  int idx = blockIdx.x * 256 + threadIdx.x;
  int c = idx / K, k = idx - c * K;
  out[idx] = f2h(in[k * 1024 + c]);
}

// x [b][t][128] f32 -> xb [(t*64+b)][128] f16
__global__ void k_cvtx(const float* __restrict__ x, unsigned short* __restrict__ xb) {
  int i = blockIdx.x * 256 + threadIdx.x;
  int o = i * 4;
  int k = o & 127, row = o >> 7;
  int b = row & 63, t = row >> 6;
  const f32x4 v = *(const f32x4*)(x + (size_t)((b << 10) + t) * 128 + k);
  ushort4v r;
  r.x = f2h(v.x); r.y = f2h(v.y); r.z = f2h(v.z); r.w = f2h(v.w);
  *(ushort4v*)(xb + o) = r;
}

// zx GEMM: A [65536 rows=(t*64+b)][K] f16 times Wt [1024][K] f16 (+bias)
// -> out [1024 t][1024 col][64 b] f16.  128x128 tiles, direct-global frags.
template<int K>
__global__ __launch_bounds__(256, 2) void k_zx(
    const unsigned short* __restrict__ A,
    const unsigned short* __restrict__ Wt_f, const unsigned short* __restrict__ Wt_b,
    const float* __restrict__ bias_f, const float* __restrict__ bias_b,
    unsigned short* __restrict__ out_f, unsigned short* __restrict__ out_b) {
  const int tid = threadIdx.x, w = tid >> 6, l = tid & 63;
  const int l16 = l & 15, lg = l >> 4;
  const int wm = w & 1, wn = w >> 1;
  const int rowbase = blockIdx.x * 128 + wm * 64;
  const int colbase = blockIdx.y * 128 + wn * 64;
  const unsigned short* Wt = blockIdx.z ? Wt_b : Wt_f;
  const float* bias = blockIdx.z ? bias_b : bias_f;
  unsigned short* out = blockIdx.z ? out_b : out_f;

  f32x4 acc[4][4];
#pragma unroll
  for (int nt = 0; nt < 4; nt++) {
    float bv = bias[colbase + nt * 16 + l16];
#pragma unroll
    for (int mt = 0; mt < 4; mt++) acc[mt][nt] = (f32x4){bv, bv, bv, bv};
  }

  for (int kf = 0; kf < K / 32; kf++) {
    const int ko = kf * 32 + lg * 8;
    half8 a[4], b[4];
#pragma unroll
    for (int mt = 0; mt < 4; mt++)
      a[mt] = *(const half8*)(A + (size_t)(rowbase + mt * 16 + l16) * K + ko);
#pragma unroll
    for (int nt = 0; nt < 4; nt++)
      b[nt] = *(const half8*)(Wt + (size_t)(colbase + nt * 16 + l16) * K + ko);
#pragma unroll
    for (int mt = 0; mt < 4; mt++)
#pragma unroll
      for (int nt = 0; nt < 4; nt++)
        acc[mt][nt] = __builtin_amdgcn_mfma_f32_16x16x32_f16(a[mt], b[nt], acc[mt][nt], 0, 0, 0);
  }

#pragma unroll
  for (int mt = 0; mt < 4; mt++) {
    const int rowchunk = rowbase + mt * 16;
    const int t = rowchunk >> 6;
    const int b0 = (rowchunk & 63) + lg * 4;
#pragma unroll
    for (int nt = 0; nt < 4; nt++) {
      const int c = colbase + nt * 16 + l16;
      ushort4v r;
      r.x = f2h(acc[mt][nt].x); r.y = f2h(acc[mt][nt].y);
      r.z = f2h(acc[mt][nt].z); r.w = f2h(acc[mt][nt].w);
      *(ushort4v*)(out + (((size_t)t << 10 | c) << 6) + b0) = r;
    }
  }
}

// Persistent recurrence. 16 WGs x 576 thr: bid = half*8 + d*4 + g.
// Waves 0..7 compute (u-tile of 16 each, half-U resident); wave 8 = comm.
// Exchange: L1 exch = h1 [(tt*64+b)][512] (doubles as LN input);
//           L2 exch = hist [t][d][g][half][16 b][128 u].
template<int LAYER>
__global__ __launch_bounds__(576, 1) void k_rec9(
    const unsigned short* __restrict__ zx_f, const unsigned short* __restrict__ zx_b,
    const unsigned short* __restrict__ Ut_f, const unsigned short* __restrict__ Ut_b,
    unsigned short* __restrict__ exch,
    float* __restrict__ out) {           // LAYER==2: [b][t][512] f32
  const int tid = threadIdx.x, wv = tid >> 6, l = tid & 63;
  const int l16 = l & 15, lg = l >> 4;
  const int bid = blockIdx.x;
  const int half = bid >> 3, d = (bid >> 2) & 1, g = bid & 3;
  const int b0 = g * 16;
  const int swz = (l16 & 7) << 3;

  const unsigned short* zx = d ? zx_b : zx_f;
  const unsigned short* Ut = d ? Ut_b : Ut_f;

  // [slot][16 b][128 u], XOR-swizzled rows; own half + partner half
  __shared__ unsigned short hlds[2 * 2048];
  __shared__ unsigned short plds[2 * 2048];

  if (wv == 8) {
    // ------------------- comm wave -------------------
    // At step t: fetch h(t-1) (published by partner at end of step t-1,
    // ~one barrier old -> visible fast), deposit in plds[(t-1)&1], then
    // hand off at barrier_mid. Idle through barrier_end.
    for (int t = 0; t < 1024; t++) {
      if (t > 0) {
        const int ts = t - 1;
        const uint4v* rowp;
        if constexpr (LAYER == 1) {
          const int trow = d ? 1023 - ts : ts;
          rowp = (const uint4v*)(exch + ((size_t)trow * 64 + b0 + l16) * 512 + d * 256 + (half ^ 1) * 128);
        } else {
          rowp = (const uint4v*)(exch + (((((size_t)ts * 2 + d) * 4 + g) * 2 + (half ^ 1)) * 2048)
                                 + (size_t)l16 * 128);
        }
        uint4v v0 = ld_b128_dev(rowp + 0 + lg);
        uint4v v1 = ld_b128_dev(rowp + 4 + lg);
        uint4v v2 = ld_b128_dev(rowp + 8 + lg);
        uint4v v3 = ld_b128_dev(rowp + 12 + lg);
        int tries = 0;
        while (true) {
          asm volatile("s_waitcnt vmcnt(0)" ::: "memory");
          __builtin_amdgcn_sched_barrier(0);
          if (__all(nosent(v0) && nosent(v1) && nosent(v2) && nosent(v3))) break;
          if (++tries > (1 << 16)) break;   // anti-hang bail
          v0 = ld_b128_dev(rowp + 0 + lg);
          v1 = ld_b128_dev(rowp + 4 + lg);
          v2 = ld_b128_dev(rowp + 8 + lg);
          v3 = ld_b128_dev(rowp + 12 + lg);
        }
        __builtin_amdgcn_sched_barrier(0);
        unsigned short* pb = plds + (ts & 1) * 2048;
        *(uint4v*)&pb[(l16 * 128 + 0 * 32 + lg * 8) ^ swz] = v0;
        *(uint4v*)&pb[(l16 * 128 + 1 * 32 + lg * 8) ^ swz] = v1;
        *(uint4v*)&pb[(l16 * 128 + 2 * 32 + lg * 8) ^ swz] = v2;
        *(uint4v*)&pb[(l16 * 128 + 3 * 32 + lg * 8) ^ swz] = v3;
        asm volatile("s_waitcnt lgkmcnt(0)" ::: "memory");
      }
      __builtin_amdgcn_s_barrier();   // barrier_mid: plds[(t-1)&1] ready
      __builtin_amdgcn_s_barrier();   // barrier_end
    }
    return;
  }

  // ------------------- compute waves (wv 0..7) -------------------
  const int ug = half * 128 + wv * 16 + l16;   // this lane's u in [0,256)

  // B[q][j]: j 0..3 = OWN kf (half*4+j), j 4..7 = REMOTE kf ((half^1)*4+j-4)
  half8 B[4][8];
#pragma unroll
  for (int j = 0; j < 8; j++) {
    const int kf = (j < 4) ? (half * 4 + j) : ((half ^ 1) * 4 + (j - 4));
#pragma unroll
    for (int q = 0; q < 4; q++)
      B[q][j] = *(const half8*)(Ut + (size_t)(q * 256 + ug) * 256 + kf * 32 + lg * 8);
  }

  f32x4 c = (f32x4){0, 0, 0, 0};

  ushort4v zq[4];
  {
    const int t0 = d ? 1023 : 0;
#pragma unroll
    for (int q = 0; q < 4; q++)
      zq[q] = *(const ushort4v*)(zx + (((size_t)t0 << 10 | (q * 256 + ug)) << 6) + b0 + lg * 4);
  }

  for (int t = 0; t < 1024; t++) {
    const int tt = d ? 1023 - t : t;
    f32x4 acc[4];
#pragma unroll
    for (int q = 0; q < 4; q++)
      acc[q] = (f32x4){h2f(zq[q].x), h2f(zq[q].y), h2f(zq[q].z), h2f(zq[q].w)};

    // own-half MFMA (overlaps comm wave's partner fetch)
    if (t > 0) {
      const int slot = ((t - 1) & 1) * 2048;
      half8 ha[4];
#pragma unroll
      for (int kfo = 0; kfo < 4; kfo++)
        ha[kfo] = *(const half8*)&hlds[slot + ((l16 * 128 + kfo * 32 + lg * 8) ^ swz)];
#pragma unroll
      for (int kfo = 0; kfo < 4; kfo++)
#pragma unroll
        for (int q = 0; q < 4; q++)
          acc[q] = __builtin_amdgcn_mfma_f32_16x16x32_f16(ha[kfo], B[q][kfo], acc[q], 0, 0, 0);
    }

    __builtin_amdgcn_s_barrier();   // barrier_mid: plds[(t-1)&1] ready

    if (t > 0) {
      const int slot = ((t - 1) & 1) * 2048;
      half8 pa[4];
#pragma unroll
      for (int kfo = 0; kfo < 4; kfo++)
        pa[kfo] = *(const half8*)&plds[slot + ((l16 * 128 + kfo * 32 + lg * 8) ^ swz)];
#pragma unroll
      for (int kfo = 0; kfo < 4; kfo++)
#pragma unroll
        for (int q = 0; q < 4; q++)
          acc[q] = __builtin_amdgcn_mfma_f32_16x16x32_f16(pa[kfo], B[q][4 + kfo], acc[q], 0, 0, 0);
    }

    if (t + 1 < 1024) {   // zx prefetch (plain loads; compiler manages waits)
      const int tn = d ? tt - 1 : tt + 1;
#pragma unroll
      for (int q = 0; q < 4; q++)
        zq[q] = *(const ushort4v*)(zx + (((size_t)tn << 10 | (q * 256 + ug)) << 6) + b0 + lg * 4);
    }

    // gates + state update; D-frag: row(b_local) = lg*4+rr, col(u) = l16
    unsigned short hb16[4];
    float hf[4];
#pragma unroll
    for (int rr = 0; rr < 4; rr++) {
      const float zi = acc[0][rr], zf = acc[1][rr], zg = acc[2][rr], zo = acc[3][rr];
      const float cc = sigf(zf) * c[rr] + sigf(zi) * tanhf_(zg);
      c[rr] = cc;
      hf[rr] = sigf(zo) * tanhf_(cc);
      hb16[rr] = f2h(hf[rr]);
    }

    // publish partner-visible h (pack lane-pairs into 4B device stores)
    {
      unsigned prt[4];
#pragma unroll
      for (int rr = 0; rr < 4; rr++)
        prt[rr] = (unsigned)__shfl_xor((int)(unsigned)hb16[rr], 1);
      const int odd = l16 & 1;
      const int rb = odd ? 2 : 0;
#pragma unroll
      for (int k = 0; k < 2; k++) {
        const int rr = rb + k;
        const int bl = lg * 4 + rr;
        const unsigned lo = odd ? prt[rr] : (unsigned)hb16[rr];
        const unsigned hi = odd ? (unsigned)hb16[rr] : prt[rr];
        const unsigned pk = (lo & 0xffffu) | (hi << 16);
        if constexpr (LAYER == 1) {
          const size_t widx = (((size_t)tt * 64 + b0 + bl) * 512 + d * 256 + (ug & ~1)) >> 1;
          st_b32_dev((unsigned*)exch + widx, pk);
        } else {
          const size_t base = ((((size_t)t * 2 + d) * 4 + g) * 2 + half) * 2048;
          const size_t widx = (base + (size_t)bl * 128 + ((ug & ~1) - half * 128)) >> 1;
          st_b32_dev((unsigned*)exch + widx, pk);
        }
      }
    }

    if constexpr (LAYER == 2) {
#pragma unroll
      for (int rr = 0; rr < 4; rr++) {
        const int b = b0 + lg * 4 + rr;
        out[((size_t)b << 10 | tt) * 512 + d * 256 + ug] = hf[rr];
      }
    }

    // own-half h(t) -> LDS (slot t&1; read next step from this slot)
#pragma unroll
    for (int rr = 0; rr < 4; rr++) {
      const int bl = lg * 4 + rr;
      const int ul = wv * 16 + l16;
      const int idx = ((bl * 128 + ul) ^ ((bl & 7) << 3)) + (t & 1) * 2048;
      hlds[idx] = hb16[rr];
    }

    // barrier_end: LDS ordering only (no vmcnt drain -> publishes fly on)
    asm volatile("s_waitcnt lgkmcnt(0)" ::: "memory");
    __builtin_amdgcn_s_barrier();
  }
}

// LayerNorm over 512 features; one wave per row. f16 in/out, f32 math.
__global__ __launch_bounds__(256) void k_ln(
    const unsigned short* __restrict__ h1, const float* __restrict__ gamma,
    const float* __restrict__ beta, unsigned short* __restrict__ ln1) {
  const int tid = threadIdx.x, w = tid >> 6, l = tid & 63;
  const size_t row = (size_t)blockIdx.x * 4 + w;
  const unsigned short* src = h1 + row * 512 + l * 8;
  const ushort4v v0 = *(const ushort4v*)src;
  const ushort4v v1 = *(const ushort4v*)(src + 4);
  float xv[8] = {h2f(v0.x), h2f(v0.y), h2f(v0.z), h2f(v0.w),
                 h2f(v1.x), h2f(v1.y), h2f(v1.z), h2f(v1.w)};
  float sum = 0.f, ssq = 0.f;
#pragma unroll
  for (int i = 0; i < 8; i++) { sum += xv[i]; ssq += xv[i] * xv[i]; }
#pragma unroll
  for (int off = 32; off; off >>= 1) {
    sum += __shfl_xor(sum, off);
    ssq += __shfl_xor(ssq, off);
  }
  const float mu = sum * (1.f / 512.f);
  const float var = ssq * (1.f / 512.f) - mu * mu;
  const float rs = __builtin_amdgcn_rsqf(var + 1e-3f);
  const f32x4 g0 = *(const f32x4*)(gamma + l * 8);
  const f32x4 g1 = *(const f32x4*)(gamma + l * 8 + 4);
  const f32x4 e0 = *(const f32x4*)(beta + l * 8);
  const f32x4 e1 = *(const f32x4*)(beta + l * 8 + 4);
  float gg[8] = {g0.x, g0.y, g0.z, g0.w, g1.x, g1.y, g1.z, g1.w};
  float ee[8] = {e0.x, e0.y, e0.z, e0.w, e1.x, e1.y, e1.z, e1.w};
  unsigned short hh[8];
#pragma unroll
  for (int i = 0; i < 8; i++)
    hh[i] = f2h((xv[i] - mu) * rs * gg[i] + ee[i]);
  unsigned short* dst = ln1 + row * 512 + l * 8;
  *(ushort4v*)dst = (ushort4v){hh[0], hh[1], hh[2], hh[3]};
  *(ushort4v*)(dst + 4) = (ushort4v){hh[4], hh[5], hh[6], hh[7]};
}

extern "C" void kernel_launch(void* const* d_in, const int* in_sizes, int n_in,
                              void* d_out, int out_size, void* d_ws, size_t ws_size,
                              hipStream_t stream) {
  (void)in_sizes; (void)n_in; (void)out_size; (void)ws_size;
  const float* x     = (const float*)d_in[0];
  const float* W1f   = (const float*)d_in[1];
  const float* U1f   = (const float*)d_in[2];
  const float* b1f   = (const float*)d_in[3];
  const float* W1b   = (const float*)d_in[4];
  const float* U1b   = (const float*)d_in[5];
  const float* b1b   = (const float*)d_in[6];
  const float* gamma = (const float*)d_in[7];
  const float* beta  = (const float*)d_in[8];
  const float* W2f   = (const float*)d_in[9];
  const float* U2f   = (const float*)d_in[10];
  const float* b2f   = (const float*)d_in[11];
  const float* W2b   = (const float*)d_in[12];
  const float* U2b   = (const float*)d_in[13];
  const float* b2b   = (const float*)d_in[14];

  char* ws = (char*)d_ws;
  size_t ofs = 0;
  auto alloc = [&](size_t bytes) -> void* {
    void* p = ws + ofs;
    ofs += (bytes + 255) & ~(size_t)255;
    return p;
  };
  unsigned short* Wt1f  = (unsigned short*)alloc((size_t)1024*128*2);
  unsigned short* Wt1b  = (unsigned short*)alloc((size_t)1024*128*2);
  unsigned short* Ut1f  = (unsigned short*)alloc((size_t)1024*256*2);
  unsigned short* Ut1b  = (unsigned short*)alloc((size_t)1024*256*2);
  unsigned short* Ut2f  = (unsigned short*)alloc((size_t)1024*256*2);
  unsigned short* Ut2b  = (unsigned short*)alloc((size_t)1024*256*2);
  unsigned short* Wt2f  = (unsigned short*)alloc((size_t)1024*512*2);
  unsigned short* Wt2b  = (unsigned short*)alloc((size_t)1024*512*2);
  unsigned short* zxf   = (unsigned short*)alloc((size_t)1024*1024*64*2);  // 128MB
  unsigned short* zxb   = (unsigned short*)alloc((size_t)1024*1024*64*2);  // 128MB
  const size_t HH2_BYTES = (size_t)1024*2*4*2*16*128*2;                    // 64MB
  unsigned short* hist  = (unsigned short*)alloc(HH2_BYTES);               // ws >= 323MB proven

  // d_out (128MB): xb [0,16MB) dead after zx1 -> h1 [0,64MB) sentinel-filled,
  // exchange+output of k_rec9<1>, dead after LN -> ln1 [64,128MB) dead after
  // zx2 -> final f32 out overwrites all 128MB in k_rec9<2>.
  unsigned short* xb  = (unsigned short*)d_out;
  unsigned short* h1  = (unsigned short*)d_out;
  unsigned short* ln1 = (unsigned short*)d_out + (size_t)65536 * 512;

  k_transpose<<<1024 * 128 / 256, 256, 0, stream>>>(W1f, Wt1f, 128);
  k_transpose<<<1024 * 128 / 256, 256, 0, stream>>>(W1b, Wt1b, 128);
  k_transpose<<<1024 * 256 / 256, 256, 0, stream>>>(U1f, Ut1f, 256);
  k_transpose<<<1024 * 256 / 256, 256, 0, stream>>>(U1b, Ut1b, 256);
  k_transpose<<<1024 * 512 / 256, 256, 0, stream>>>(W2f, Wt2f, 512);
  k_transpose<<<1024 * 512 / 256, 256, 0, stream>>>(W2b, Wt2b, 512);
  k_transpose<<<1024 * 256 / 256, 256, 0, stream>>>(U2f, Ut2f, 256);
  k_transpose<<<1024 * 256 / 256, 256, 0, stream>>>(U2b, Ut2b, 256);
  k_cvtx<<<8192, 256, 0, stream>>>(x, xb);

  dim3 zgrid(512, 8, 2);
  k_zx<128><<<zgrid, 256, 0, stream>>>(xb, Wt1f, Wt1b, b1f, b1b, zxf, zxb);
  k_fill<<<2048, 256, 0, stream>>>((uint4v*)h1, 65536u * 512u / 8u);
  k_rec9<1><<<16, 576, 0, stream>>>(zxf, zxb, Ut1f, Ut1b, h1, nullptr);
  k_ln<<<65536 / 4, 256, 0, stream>>>(h1, gamma, beta, ln1);
  k_zx<512><<<zgrid, 256, 0, stream>>>(ln1, Wt2f, Wt2b, b2f, b2b, zxf, zxb);
  k_fill<<<2048, 256, 0, stream>>>((uint4v*)hist, (unsigned)(HH2_BYTES / 16));
  k_rec9<2><<<16, 576, 0, stream>>>(zxf, zxb, Ut2f, Ut2b, hist, (float*)d_out);
}